// Round 5
// baseline (128.741 us; speedup 1.0000x reference)
//
#include <hip/hip_runtime.h>
#include <math.h>

// Problem constants (match reference)
constexpr int P  = 2;
constexpr int B  = 96;
constexpr int A  = 32;
constexpr int N  = B * A;      // 3072
constexpr int MD = 4;
constexpr int MA = 4;
constexpr int NPOL = MD + MA;  // 8
constexpr int SJ = 4;          // j-slices per (p,b); grid = P*B*SJ = 768 = exactly 3 blocks/CU
constexpr int JS = N / SJ;     // 768 atoms per slice
constexpr int JPT = JS / 256;  // 3 j-atoms per thread
constexpr int NB = P * B * SJ; // 768 blocks
constexpr int PB = B * SJ;     // 384 blocks per pose
constexpr float C_LK  = 0.0897935610625833f;
constexpr float LOG2E = 1.4426950408889634f;

// ws layout (floats): [bid] acc0 partial, [1024+bid] acc1 partial.
// ws layout (uints):  [4096] completion counter, [4160] untouched reference cell.
// The harness poisons ws with a UNIFORM fill each iteration, so the untouched
// reference cell holds exactly the counter's initial value V. A block is "last"
// iff (fetch_add(counter) - V) mod NB == NB-1  (mod makes it robust to replays
// that skip the re-fill). No spin, no co-residency assumption.
constexpr int CNT_IDX = 4096;
constexpr int REF_IDX = 4160;

__global__ __launch_bounds__(256) void lkball_kernel(
    const float* __restrict__ pose_coords,    // P*N*3
    const int*   __restrict__ block_type,     // P*B
    const int*   __restrict__ min_sep,        // P*B*B
    const int*   __restrict__ all_bonds,      // NT*A*2
    const int*   __restrict__ bond_ranges,    // NT*A*2
    const int*   __restrict__ n_donH,         // NT
    const int*   __restrict__ n_acc,          // NT
    const int*   __restrict__ donH_inds,      // NT*MD
    const int*   __restrict__ don_hvy_inds,   // NT*MD
    const int*   __restrict__ acc_inds,       // NT*MA
    const int*   __restrict__ hyb,            // NT*MA
    const int*   __restrict__ is_h,           // NT*A
    const float* __restrict__ lk_params,      // NT*A*4
    const int*   __restrict__ path_dist,      // NT*A*A
    const float* __restrict__ glob,           // cutoff, ramp2, d2_low
    const float* __restrict__ wglob,          // wdist, wang
    const float* __restrict__ sp2t,
    const float* __restrict__ sp3t,
    const float* __restrict__ ringt,
    float*       __restrict__ ws,             // per-block partials + counter
    float*       __restrict__ out)            // 2*P
{
    __shared__ float spolar[NPOL][16];
    __shared__ int   spath[NPOL * A];
    __shared__ float red0[4], red1[4];
    __shared__ int   sIsLast;

    const int bid   = blockIdx.x;
    const int p     = bid / PB;
    const int rem   = bid % PB;
    const int b     = rem / SJ;
    const int slice = rem % SJ;
    const int tid   = threadIdx.x;

    // Same-address broadcast load: one L2 request for the whole wave.
    const int bt_b = block_type[p * B + b];

    // ---- j-register phase FIRST: zero dependence on LDS/setup, so these cold
    //      HBM loads issue immediately and overlap the polar setup chain.
    const int a_j   = tid & 31;          // constant across i (256 % 32 == 0)
    const int jbase = slice * JS + tid;

    float cx[JPT], cy[JPT], cz[JPT], rj[JPT], ve[JPT], msep_f[JPT];
    int   intra[JPT];
#pragma unroll
    for (int i = 0; i < JPT; ++i) {
        const int j   = jbase + 256 * i;
        const int b_j = j >> 5;              // constant per 32-lane group
        const float* cj = pose_coords + (size_t)(p * N + j) * 3;
        cx[i] = cj[0]; cy[i] = cj[1]; cz[i] = cj[2];
        const int bt_j = block_type[p * B + b_j];         // broadcast
        const int hv   = is_h[bt_j * A + a_j];            // coalesced
        const float4 pj = *(const float4*)(lk_params + (size_t)(bt_j * A + a_j) * 4);
        rj[i] = pj.x;
        ve[i] = hv ? 0.0f : pj.w;            // heavy-mask folded into vol_j
        msep_f[i] = (float)min_sep[(p * B + b) * B + b_j]; // broadcast
        intra[i]  = (b_j == b);
    }

    // ---- path-distance rows for all 8 polars (256 threads = 8*32), 2-hop chain
    {
        const int k  = tid >> 5;
        const int aj = tid & 31;
        const int ak = (k < MD) ? don_hvy_inds[bt_b * MD + k]
                                : acc_inds[bt_b * MA + (k - MD)];
        spath[tid] = path_dist[(bt_b * A + ak) * A + aj];
    }

    // ---- wave 0: polar records. 8 redundant 8-lane groups (k = tid&7) so the
    //      bond-graph traversal uses wave-wide __shfl on preloaded rows instead
    //      of 4 dependent cold-memory hops.
    if (tid < 64) {
        const int la = tid & 31;
        const int2 rr = *(const int2*)(bond_ranges + (size_t)(bt_b * A + la) * 2);
        const int2 bb = *(const int2*)(all_bonds   + (size_t)(bt_b * A + la) * 2);
        const int r0v = rr.x;   // bond_ranges[bt][atom=la][0]
        const int b1v = bb.y;   // all_bonds[bt][atom=la][1]

        const int k  = tid & 7;
        const int kk = k - MD;
        const bool isacc = (k >= MD);

        int a_i, valid, Hi = 0;
        if (isacc) {
            valid = (kk < n_acc[bt_b]) ? 1 : 0;
            a_i   = acc_inds[bt_b * MA + kk];
        } else {
            valid = (k < n_donH[bt_b]) ? 1 : 0;
            a_i   = don_hvy_inds[bt_b * MD + k];
            Hi    = donH_inds[bt_b * MD + k];
        }

        // Wave-uniform shuffle chain (all 64 lanes active; donors use idx 0).
        const int i0    = isacc ? (a_i & 31) : 0;
        const int r0    = __shfl(r0v, i0);
        const int base  = __shfl(b1v, r0 & 31);
        const int r0b   = __shfl(r0v, base & 31);
        const int base2 = __shfl(b1v, r0b & 31);

        // Polar params load issues in parallel with the coords loads below.
        const float4 prv = *(const float4*)(lk_params + (size_t)(bt_b * A + a_i) * 4);

        const float wdist = wglob[0];
        const float wang  = wglob[1];
        float xp[3], w0[3], w1[3];
        if (!isacc) {
            const float* hc = pose_coords + (size_t)(p * N + b * A + a_i) * 3;
            const float* Hc = pose_coords + (size_t)(p * N + b * A + Hi)  * 3;
            float dx = Hc[0] - hc[0], dy = Hc[1] - hc[1], dz = Hc[2] - hc[2];
            float inv = 1.0f / sqrtf(dx * dx + dy * dy + dz * dz + 1e-12f);
            xp[0] = hc[0]; xp[1] = hc[1]; xp[2] = hc[2];
            w0[0] = hc[0] + wdist * dx * inv;
            w0[1] = hc[1] + wdist * dy * inv;
            w0[2] = hc[2] + wdist * dz * inv;
            // donor's second water is always masked (never read in donor loop)
            w1[0] = hc[0] + 1.0e3f; w1[1] = hc[1] + 1.0e3f; w1[2] = hc[2] + 1.0e3f;
        } else {
            const float* c  = pose_coords + (size_t)(p * N + b * A + a_i)   * 3;
            const float* bx = pose_coords + (size_t)(p * N + b * A + base)  * 3;
            const float* ax = pose_coords + (size_t)(p * N + b * A + base2) * 3;

            float e1x = c[0] - bx[0], e1y = c[1] - bx[1], e1z = c[2] - bx[2];
            float inv1 = 1.0f / sqrtf(e1x * e1x + e1y * e1y + e1z * e1z + 1e-12f);
            e1x *= inv1; e1y *= inv1; e1z *= inv1;

            float ux = bx[0] - ax[0], uy = bx[1] - ax[1], uz = bx[2] - ax[2];
            float nx = uy * e1z - uz * e1y;
            float ny = uz * e1x - ux * e1z;
            float nz = ux * e1y - uy * e1x;
            float inv2 = 1.0f / sqrtf(nx * nx + ny * ny + nz * nz + 1e-12f);
            nx *= inv2; ny *= inv2; nz *= inv2;
            float e2x = ny * e1z - nz * e1y;
            float e2y = nz * e1x - nx * e1z;
            float e2z = nx * e1y - ny * e1x;

            const int hy = hyb[bt_b * MA + kk];
            const float* tab = (hy == 0) ? sp2t : ((hy == 1) ? sp3t : ringt);
            const float ct = cosf(wang), st = sinf(wang);
            float c0 = cosf(tab[0]), s0 = sinf(tab[0]);
            float c1 = cosf(tab[1]), s1 = sinf(tab[1]);

            xp[0] = c[0]; xp[1] = c[1]; xp[2] = c[2];
            w0[0] = c[0] - wdist * ct * e1x + wdist * st * c0 * e2x + wdist * st * s0 * nx;
            w0[1] = c[1] - wdist * ct * e1y + wdist * st * c0 * e2y + wdist * st * s0 * ny;
            w0[2] = c[2] - wdist * ct * e1z + wdist * st * c0 * e2z + wdist * st * s0 * nz;
            w1[0] = c[0] - wdist * ct * e1x + wdist * st * c1 * e2x + wdist * st * s1 * nx;
            w1[1] = c[1] - wdist * ct * e1y + wdist * st * c1 * e2y + wdist * st * s1 * ny;
            w1[2] = c[2] - wdist * ct * e1z + wdist * st * c1 * e2z + wdist * st * s1 * nz;
        }
        if (tid < NPOL) {   // only the first redundant copy writes
            const float lam = prv.z;
            spolar[k][0] = xp[0]; spolar[k][1] = xp[1]; spolar[k][2] = xp[2];
            spolar[k][3] = w0[0]; spolar[k][4] = w0[1]; spolar[k][5] = w0[2];
            spolar[k][6] = w1[0]; spolar[k][7] = w1[1]; spolar[k][8] = w1[2];
            spolar[k][9]  = prv.x;
            spolar[k][10] = valid ? (C_LK * prv.y / lam) : 0.0f;
            spolar[k][11] = -LOG2E / (lam * lam);
        }
    }
    __syncthreads();   // single barrier

    const float cutoff2   = glob[0] * glob[0];
    const float inv_ramp2 = 1.0f / glob[1];
    const float c4        = (glob[2] + glob[1]) * inv_ramp2;  // (d2_low+ramp2)/ramp2

    float acc0 = 0.0f, acc1 = 0.0f;

    // ---- Donor polars (k < MD): single water w0
#pragma unroll
    for (int k = 0; k < MD; ++k) {
        const float4 q0 = ((const float4*)spolar[k])[0];  // xp.xyz, w0.x
        const float4 q1 = ((const float4*)spolar[k])[1];  // w0.yz, w1.xy
        const float4 q2 = ((const float4*)spolar[k])[2];  // w1.z, ri, pref, negq
        const float px  = q0.x, py  = q0.y, pz  = q0.z;
        const float w0x = q0.w, w0y = q1.x, w0z = q1.y;
        const float ri  = q2.y, pref = q2.z, negq = q2.w;
        const float path_k = (float)spath[k * A + a_j];

        float rij[JPT], pv[JPT];
#pragma unroll
        for (int i = 0; i < JPT; ++i) { rij[i] = ri + rj[i]; pv[i] = pref * ve[i]; }

#pragma unroll
        for (int i = 0; i < JPT; ++i) {
            const float dx = px - cx[i], dy = py - cy[i], dz = pz - cz[i];
            float d2 = fmaf(dx, dx, fmaf(dy, dy, dz * dz));
            d2 = fmaxf(d2, 0.01f);
            const float rinv = __builtin_amdgcn_rsqf(d2);
            const float d = d2 * rinv;
            const float sep = intra[i] ? path_k : msep_f[i];
            const bool ok = (sep >= 4.0f) & (d2 < cutoff2);

            const float t = d - rij[i];
            const float e = __builtin_amdgcn_exp2f(t * t * negq);
            float lk = pv[i] * e * (rinv * rinv);
            lk = ok ? lk : 0.0f;

            const float d0x = w0x - cx[i], d0y = w0y - cy[i], d0z = w0z - cz[i];
            const float d2wmin = fmaf(d0x, d0x, fmaf(d0y, d0y, d0z * d0z));
            float wt = fmaf(d2wmin, -inv_ramp2, c4);
            wt = fminf(fmaxf(wt, 0.0f), 1.0f);
            const float frac = wt * wt * fmaf(-2.0f, wt, 3.0f);

            acc0 += lk;
            acc1 = fmaf(lk, frac, acc1);
        }
    }

    // ---- Acceptor polars (k >= MD): two waters
#pragma unroll
    for (int k = MD; k < NPOL; ++k) {
        const float4 q0 = ((const float4*)spolar[k])[0];
        const float4 q1 = ((const float4*)spolar[k])[1];
        const float4 q2 = ((const float4*)spolar[k])[2];
        const float px  = q0.x, py  = q0.y, pz  = q0.z;
        const float w0x = q0.w, w0y = q1.x, w0z = q1.y;
        const float w1x = q1.z, w1y = q1.w, w1z = q2.x;
        const float ri  = q2.y, pref = q2.z, negq = q2.w;
        const float path_k = (float)spath[k * A + a_j];

        float rij[JPT], pv[JPT];
#pragma unroll
        for (int i = 0; i < JPT; ++i) { rij[i] = ri + rj[i]; pv[i] = pref * ve[i]; }

#pragma unroll
        for (int i = 0; i < JPT; ++i) {
            const float dx = px - cx[i], dy = py - cy[i], dz = pz - cz[i];
            float d2 = fmaf(dx, dx, fmaf(dy, dy, dz * dz));
            d2 = fmaxf(d2, 0.01f);
            const float rinv = __builtin_amdgcn_rsqf(d2);
            const float d = d2 * rinv;
            const float sep = intra[i] ? path_k : msep_f[i];
            const bool ok = (sep >= 4.0f) & (d2 < cutoff2);

            const float t = d - rij[i];
            const float e = __builtin_amdgcn_exp2f(t * t * negq);
            float lk = pv[i] * e * (rinv * rinv);
            lk = ok ? lk : 0.0f;

            const float d0x = w0x - cx[i], d0y = w0y - cy[i], d0z = w0z - cz[i];
            const float d1x = w1x - cx[i], d1y = w1y - cy[i], d1z = w1z - cz[i];
            const float d2w0 = fmaf(d0x, d0x, fmaf(d0y, d0y, d0z * d0z));
            const float d2w1 = fmaf(d1x, d1x, fmaf(d1y, d1y, d1z * d1z));
            const float d2wmin = fminf(d2w0, d2w1);
            float wt = fmaf(d2wmin, -inv_ramp2, c4);
            wt = fminf(fmaxf(wt, 0.0f), 1.0f);
            const float frac = wt * wt * fmaf(-2.0f, wt, 3.0f);

            acc0 += lk;
            acc1 = fmaf(lk, frac, acc1);
        }
    }

    // ---- Block reduce: wave shuffle -> LDS
    for (int off = 32; off > 0; off >>= 1) {
        acc0 += __shfl_down(acc0, off);
        acc1 += __shfl_down(acc1, off);
    }
    const int wave = tid >> 6;
    const int lane = tid & 63;
    if (lane == 0) { red0[wave] = acc0; red1[wave] = acc1; }
    __syncthreads();

    // ---- Publish partials (agent-scope release) + last-block detection.
    if (tid == 0) {
        const float s0 = red0[0] + red0[1] + red0[2] + red0[3];
        const float s1 = red1[0] + red1[1] + red1[2] + red1[3];
        __hip_atomic_store(&ws[bid],        s0, __ATOMIC_RELEASE, __HIP_MEMORY_SCOPE_AGENT);
        __hip_atomic_store(&ws[1024 + bid], s1, __ATOMIC_RELEASE, __HIP_MEMORY_SCOPE_AGENT);
        unsigned int* wsu = (unsigned int*)ws;
        // Reference cell: never written, still holds the poison value == the
        // counter's initial value (uniform fill).
        const unsigned int V   = __hip_atomic_load(&wsu[REF_IDX], __ATOMIC_RELAXED, __HIP_MEMORY_SCOPE_AGENT);
        const unsigned int old = __hip_atomic_fetch_add(&wsu[CNT_IDX], 1u, __ATOMIC_ACQ_REL, __HIP_MEMORY_SCOPE_AGENT);
        sIsLast = (((old - V) % (unsigned int)NB) == (unsigned int)(NB - 1)) ? 1 : 0;
    }
    __syncthreads();

    // ---- Last block performs the final reduction (4 waves, one output each).
    if (sIsLast) {
        const int base = (wave >> 1) * 1024 + (wave & 1) * PB;
        float s = 0.0f;
        for (int i = lane; i < PB; i += 64)
            s += __hip_atomic_load(&ws[base + i], __ATOMIC_RELAXED, __HIP_MEMORY_SCOPE_AGENT);
        for (int off = 32; off > 0; off >>= 1) s += __shfl_down(s, off);
        if (lane == 0) out[(wave >> 1) * P + (wave & 1)] = s;
    }
}

extern "C" void kernel_launch(void* const* d_in, const int* in_sizes, int n_in,
                              void* d_out, int out_size, void* d_ws, size_t ws_size,
                              hipStream_t stream) {
    const float* pose_coords  = (const float*)d_in[0];
    const int*   block_type   = (const int*)  d_in[1];
    const int*   min_sep      = (const int*)  d_in[2];
    const int*   all_bonds    = (const int*)  d_in[4];
    const int*   bond_ranges  = (const int*)  d_in[5];
    const int*   n_donH       = (const int*)  d_in[6];
    const int*   n_acc        = (const int*)  d_in[7];
    const int*   donH_inds    = (const int*)  d_in[8];
    const int*   don_hvy_inds = (const int*)  d_in[9];
    const int*   acc_inds     = (const int*)  d_in[10];
    const int*   hyb          = (const int*)  d_in[11];
    const int*   is_h         = (const int*)  d_in[12];
    const float* lk_params    = (const float*)d_in[13];
    const int*   path_dist    = (const int*)  d_in[14];
    const float* glob         = (const float*)d_in[15];
    const float* wglob        = (const float*)d_in[16];
    const float* sp2t         = (const float*)d_in[17];
    const float* sp3t         = (const float*)d_in[18];
    const float* ringt        = (const float*)d_in[19];
    float* out = (float*)d_out;
    float* ws  = (float*)d_ws;

    // Single launch: last finishing block reduces partials and writes out.
    lkball_kernel<<<NB, 256, 0, stream>>>(
        pose_coords, block_type, min_sep, all_bonds, bond_ranges,
        n_donH, n_acc, donH_inds, don_hvy_inds, acc_inds, hyb, is_h,
        lk_params, path_dist, glob, wglob, sp2t, sp3t, ringt, ws, out);
}

// Round 6
// 106.757 us; speedup vs baseline: 1.2059x; 1.2059x over previous
//
#include <hip/hip_runtime.h>
#include <math.h>

// Problem constants (match reference)
constexpr int P  = 2;
constexpr int B  = 96;
constexpr int A  = 32;
constexpr int N  = B * A;      // 3072
constexpr int MD = 4;
constexpr int MA = 4;
constexpr int NPOL = MD + MA;  // 8
constexpr int SJ = 12;         // j-slices per (p,b); grid = P*B*SJ = 2304 = 9 blocks/CU
constexpr int JS = N / SJ;     // 256 atoms per slice
constexpr int JPT = JS / 256;  // 1 j-atom per thread
constexpr int NB = P * B * SJ; // 2304 blocks
constexpr int PB = B * SJ;     // 1152 blocks per pose
constexpr float C_LK  = 0.0897935610625833f;
constexpr float LOG2E = 1.4426950408889634f;

// ws layout (floats): ws[bid] = partial acc0, ws[2560+bid] = partial acc1.
// Plain stores only — NO ordered agent-scope atomics (round-5 lesson: they emit
// per-block L2 writeback/invalidate on gfx950's non-coherent XCD L2s, 4-5x
// kernel slowdown). Kernel boundary provides the coherence for the reducer.
constexpr int ACC1_OFF = 2560;

__global__ __launch_bounds__(256) void lkball_kernel(
    const float* __restrict__ pose_coords,    // P*N*3
    const int*   __restrict__ block_type,     // P*B
    const int*   __restrict__ min_sep,        // P*B*B
    const int*   __restrict__ all_bonds,      // NT*A*2
    const int*   __restrict__ bond_ranges,    // NT*A*2
    const int*   __restrict__ n_donH,         // NT
    const int*   __restrict__ n_acc,          // NT
    const int*   __restrict__ donH_inds,      // NT*MD
    const int*   __restrict__ don_hvy_inds,   // NT*MD
    const int*   __restrict__ acc_inds,       // NT*MA
    const int*   __restrict__ hyb,            // NT*MA
    const int*   __restrict__ is_h,           // NT*A
    const float* __restrict__ lk_params,      // NT*A*4
    const int*   __restrict__ path_dist,      // NT*A*A
    const float* __restrict__ glob,           // cutoff, ramp2, d2_low
    const float* __restrict__ wglob,          // wdist, wang
    const float* __restrict__ sp2t,
    const float* __restrict__ sp3t,
    const float* __restrict__ ringt,
    float*       __restrict__ ws)             // per-block partials
{
    __shared__ float spolar[NPOL][16];
    __shared__ int   spath[NPOL * A];
    __shared__ float red0[4], red1[4];

    const int bid   = blockIdx.x;
    const int p     = bid / PB;
    const int rem   = bid % PB;
    const int b     = rem / SJ;
    const int slice = rem % SJ;
    const int tid   = threadIdx.x;

    // Same-address broadcast load: one L2 request for the whole wave.
    const int bt_b = block_type[p * B + b];

    // ---- j-register phase FIRST: zero dependence on LDS/setup, so these cold
    //      HBM loads issue immediately and overlap the polar setup chain.
    const int a_j   = tid & 31;          // constant across i (256 % 32 == 0)
    const int jbase = slice * JS + tid;

    float cx[JPT], cy[JPT], cz[JPT], rj[JPT], ve[JPT], msep_f[JPT];
    int   intra[JPT];
#pragma unroll
    for (int i = 0; i < JPT; ++i) {
        const int j   = jbase + 256 * i;
        const int b_j = j >> 5;              // constant per 32-lane group
        const float* cj = pose_coords + (size_t)(p * N + j) * 3;
        cx[i] = cj[0]; cy[i] = cj[1]; cz[i] = cj[2];
        const int bt_j = block_type[p * B + b_j];         // broadcast
        const int hv   = is_h[bt_j * A + a_j];            // coalesced
        const float4 pj = *(const float4*)(lk_params + (size_t)(bt_j * A + a_j) * 4);
        rj[i] = pj.x;
        ve[i] = hv ? 0.0f : pj.w;            // heavy-mask folded into vol_j
        msep_f[i] = (float)min_sep[(p * B + b) * B + b_j]; // broadcast
        intra[i]  = (b_j == b);
    }

    // ---- path-distance rows for all 8 polars (256 threads = 8*32), 2-hop chain
    {
        const int k  = tid >> 5;
        const int aj = tid & 31;
        const int ak = (k < MD) ? don_hvy_inds[bt_b * MD + k]
                                : acc_inds[bt_b * MA + (k - MD)];
        spath[tid] = path_dist[(bt_b * A + ak) * A + aj];
    }

    // ---- wave 0: polar records. 8 redundant 8-lane groups (k = tid&7) so the
    //      bond-graph traversal uses wave-wide __shfl on preloaded rows instead
    //      of 4 dependent cold-memory hops.
    if (tid < 64) {
        const int la = tid & 31;
        const int2 rr = *(const int2*)(bond_ranges + (size_t)(bt_b * A + la) * 2);
        const int2 bb = *(const int2*)(all_bonds   + (size_t)(bt_b * A + la) * 2);
        const int r0v = rr.x;   // bond_ranges[bt][atom=la][0]
        const int b1v = bb.y;   // all_bonds[bt][atom=la][1]

        const int k  = tid & 7;
        const int kk = k - MD;
        const bool isacc = (k >= MD);

        int a_i, valid, Hi = 0;
        if (isacc) {
            valid = (kk < n_acc[bt_b]) ? 1 : 0;
            a_i   = acc_inds[bt_b * MA + kk];
        } else {
            valid = (k < n_donH[bt_b]) ? 1 : 0;
            a_i   = don_hvy_inds[bt_b * MD + k];
            Hi    = donH_inds[bt_b * MD + k];
        }

        // Wave-uniform shuffle chain (all 64 lanes active; donors use idx 0).
        const int i0    = isacc ? (a_i & 31) : 0;
        const int r0    = __shfl(r0v, i0);
        const int base  = __shfl(b1v, r0 & 31);
        const int r0b   = __shfl(r0v, base & 31);
        const int base2 = __shfl(b1v, r0b & 31);

        // Polar params load issues in parallel with the coords loads below.
        const float4 prv = *(const float4*)(lk_params + (size_t)(bt_b * A + a_i) * 4);

        const float wdist = wglob[0];
        const float wang  = wglob[1];
        float xp[3], w0[3], w1[3];
        if (!isacc) {
            const float* hc = pose_coords + (size_t)(p * N + b * A + a_i) * 3;
            const float* Hc = pose_coords + (size_t)(p * N + b * A + Hi)  * 3;
            float dx = Hc[0] - hc[0], dy = Hc[1] - hc[1], dz = Hc[2] - hc[2];
            float inv = 1.0f / sqrtf(dx * dx + dy * dy + dz * dz + 1e-12f);
            xp[0] = hc[0]; xp[1] = hc[1]; xp[2] = hc[2];
            w0[0] = hc[0] + wdist * dx * inv;
            w0[1] = hc[1] + wdist * dy * inv;
            w0[2] = hc[2] + wdist * dz * inv;
            // donor's second water is always masked (never read in donor loop)
            w1[0] = hc[0] + 1.0e3f; w1[1] = hc[1] + 1.0e3f; w1[2] = hc[2] + 1.0e3f;
        } else {
            const float* c  = pose_coords + (size_t)(p * N + b * A + a_i)   * 3;
            const float* bx = pose_coords + (size_t)(p * N + b * A + base)  * 3;
            const float* ax = pose_coords + (size_t)(p * N + b * A + base2) * 3;

            float e1x = c[0] - bx[0], e1y = c[1] - bx[1], e1z = c[2] - bx[2];
            float inv1 = 1.0f / sqrtf(e1x * e1x + e1y * e1y + e1z * e1z + 1e-12f);
            e1x *= inv1; e1y *= inv1; e1z *= inv1;

            float ux = bx[0] - ax[0], uy = bx[1] - ax[1], uz = bx[2] - ax[2];
            float nx = uy * e1z - uz * e1y;
            float ny = uz * e1x - ux * e1z;
            float nz = ux * e1y - uy * e1x;
            float inv2 = 1.0f / sqrtf(nx * nx + ny * ny + nz * nz + 1e-12f);
            nx *= inv2; ny *= inv2; nz *= inv2;
            float e2x = ny * e1z - nz * e1y;
            float e2y = nz * e1x - nx * e1z;
            float e2z = nx * e1y - ny * e1x;

            const int hy = hyb[bt_b * MA + kk];
            const float* tab = (hy == 0) ? sp2t : ((hy == 1) ? sp3t : ringt);
            const float ct = cosf(wang), st = sinf(wang);
            float c0 = cosf(tab[0]), s0 = sinf(tab[0]);
            float c1 = cosf(tab[1]), s1 = sinf(tab[1]);

            xp[0] = c[0]; xp[1] = c[1]; xp[2] = c[2];
            w0[0] = c[0] - wdist * ct * e1x + wdist * st * c0 * e2x + wdist * st * s0 * nx;
            w0[1] = c[1] - wdist * ct * e1y + wdist * st * c0 * e2y + wdist * st * s0 * ny;
            w0[2] = c[2] - wdist * ct * e1z + wdist * st * c0 * e2z + wdist * st * s0 * nz;
            w1[0] = c[0] - wdist * ct * e1x + wdist * st * c1 * e2x + wdist * st * s1 * nx;
            w1[1] = c[1] - wdist * ct * e1y + wdist * st * c1 * e2y + wdist * st * s1 * ny;
            w1[2] = c[2] - wdist * ct * e1z + wdist * st * c1 * e2z + wdist * st * s1 * nz;
        }
        if (tid < NPOL) {   // only the first redundant copy writes
            const float lam = prv.z;
            spolar[k][0] = xp[0]; spolar[k][1] = xp[1]; spolar[k][2] = xp[2];
            spolar[k][3] = w0[0]; spolar[k][4] = w0[1]; spolar[k][5] = w0[2];
            spolar[k][6] = w1[0]; spolar[k][7] = w1[1]; spolar[k][8] = w1[2];
            spolar[k][9]  = prv.x;
            spolar[k][10] = valid ? (C_LK * prv.y / lam) : 0.0f;
            spolar[k][11] = -LOG2E / (lam * lam);
        }
    }
    __syncthreads();   // single barrier

    const float cutoff2   = glob[0] * glob[0];
    const float inv_ramp2 = 1.0f / glob[1];
    const float c4        = (glob[2] + glob[1]) * inv_ramp2;  // (d2_low+ramp2)/ramp2

    float acc0 = 0.0f, acc1 = 0.0f;

    // ---- Donor polars (k < MD): single water w0
#pragma unroll
    for (int k = 0; k < MD; ++k) {
        const float4 q0 = ((const float4*)spolar[k])[0];  // xp.xyz, w0.x
        const float4 q1 = ((const float4*)spolar[k])[1];  // w0.yz, w1.xy
        const float4 q2 = ((const float4*)spolar[k])[2];  // w1.z, ri, pref, negq
        const float px  = q0.x, py  = q0.y, pz  = q0.z;
        const float w0x = q0.w, w0y = q1.x, w0z = q1.y;
        const float ri  = q2.y, pref = q2.z, negq = q2.w;
        const float path_k = (float)spath[k * A + a_j];

#pragma unroll
        for (int i = 0; i < JPT; ++i) {
            const float dx = px - cx[i], dy = py - cy[i], dz = pz - cz[i];
            float d2 = fmaf(dx, dx, fmaf(dy, dy, dz * dz));
            d2 = fmaxf(d2, 0.01f);
            const float rinv = __builtin_amdgcn_rsqf(d2);
            const float d = d2 * rinv;
            const float sep = intra[i] ? path_k : msep_f[i];
            const bool ok = (sep >= 4.0f) & (d2 < cutoff2);

            const float t = d - ri - rj[i];
            const float e = __builtin_amdgcn_exp2f(t * t * negq);
            float lk = pref * ve[i] * e * (rinv * rinv);
            lk = ok ? lk : 0.0f;

            const float d0x = w0x - cx[i], d0y = w0y - cy[i], d0z = w0z - cz[i];
            const float d2wmin = fmaf(d0x, d0x, fmaf(d0y, d0y, d0z * d0z));
            float wt = fmaf(d2wmin, -inv_ramp2, c4);
            wt = fminf(fmaxf(wt, 0.0f), 1.0f);
            const float frac = wt * wt * fmaf(-2.0f, wt, 3.0f);

            acc0 += lk;
            acc1 = fmaf(lk, frac, acc1);
        }
    }

    // ---- Acceptor polars (k >= MD): two waters
#pragma unroll
    for (int k = MD; k < NPOL; ++k) {
        const float4 q0 = ((const float4*)spolar[k])[0];
        const float4 q1 = ((const float4*)spolar[k])[1];
        const float4 q2 = ((const float4*)spolar[k])[2];
        const float px  = q0.x, py  = q0.y, pz  = q0.z;
        const float w0x = q0.w, w0y = q1.x, w0z = q1.y;
        const float w1x = q1.z, w1y = q1.w, w1z = q2.x;
        const float ri  = q2.y, pref = q2.z, negq = q2.w;
        const float path_k = (float)spath[k * A + a_j];

#pragma unroll
        for (int i = 0; i < JPT; ++i) {
            const float dx = px - cx[i], dy = py - cy[i], dz = pz - cz[i];
            float d2 = fmaf(dx, dx, fmaf(dy, dy, dz * dz));
            d2 = fmaxf(d2, 0.01f);
            const float rinv = __builtin_amdgcn_rsqf(d2);
            const float d = d2 * rinv;
            const float sep = intra[i] ? path_k : msep_f[i];
            const bool ok = (sep >= 4.0f) & (d2 < cutoff2);

            const float t = d - ri - rj[i];
            const float e = __builtin_amdgcn_exp2f(t * t * negq);
            float lk = pref * ve[i] * e * (rinv * rinv);
            lk = ok ? lk : 0.0f;

            const float d0x = w0x - cx[i], d0y = w0y - cy[i], d0z = w0z - cz[i];
            const float d1x = w1x - cx[i], d1y = w1y - cy[i], d1z = w1z - cz[i];
            const float d2w0 = fmaf(d0x, d0x, fmaf(d0y, d0y, d0z * d0z));
            const float d2w1 = fmaf(d1x, d1x, fmaf(d1y, d1y, d1z * d1z));
            const float d2wmin = fminf(d2w0, d2w1);
            float wt = fmaf(d2wmin, -inv_ramp2, c4);
            wt = fminf(fmaxf(wt, 0.0f), 1.0f);
            const float frac = wt * wt * fmaf(-2.0f, wt, 3.0f);

            acc0 += lk;
            acc1 = fmaf(lk, frac, acc1);
        }
    }

    // ---- Reduce: wave shuffle -> LDS -> one plain store pair per block (NO atomics)
    for (int off = 32; off > 0; off >>= 1) {
        acc0 += __shfl_down(acc0, off);
        acc1 += __shfl_down(acc1, off);
    }
    const int wave = tid >> 6;
    const int lane = tid & 63;
    if (lane == 0) { red0[wave] = acc0; red1[wave] = acc1; }
    __syncthreads();
    if (tid == 0) {
        ws[bid]            = red0[0] + red0[1] + red0[2] + red0[3];
        ws[ACC1_OFF + bid] = red1[0] + red1[1] + red1[2] + red1[3];
    }
}

// One block: 4 waves, one per output value. No atomics, overwrites out fully.
__global__ __launch_bounds__(256) void reduce_kernel(
    const float* __restrict__ ws, float* __restrict__ out)
{
    const int wave = threadIdx.x >> 6;
    const int lane = threadIdx.x & 63;
    // wave0: out[0]=acc0,p0 ws[0..1151]           wave1: out[1]=acc0,p1 ws[1152..2303]
    // wave2: out[2]=acc1,p0 ws[2560..3711]        wave3: out[3]=acc1,p1 ws[3712..4863]
    const int base = (wave >> 1) * ACC1_OFF + (wave & 1) * PB;
    float s = 0.0f;
    for (int i = lane; i < PB; i += 64) s += ws[base + i];
    for (int off = 32; off > 0; off >>= 1) s += __shfl_down(s, off);
    if (lane == 0) out[(wave >> 1) * P + (wave & 1)] = s;
}

extern "C" void kernel_launch(void* const* d_in, const int* in_sizes, int n_in,
                              void* d_out, int out_size, void* d_ws, size_t ws_size,
                              hipStream_t stream) {
    const float* pose_coords  = (const float*)d_in[0];
    const int*   block_type   = (const int*)  d_in[1];
    const int*   min_sep      = (const int*)  d_in[2];
    const int*   all_bonds    = (const int*)  d_in[4];
    const int*   bond_ranges  = (const int*)  d_in[5];
    const int*   n_donH       = (const int*)  d_in[6];
    const int*   n_acc        = (const int*)  d_in[7];
    const int*   donH_inds    = (const int*)  d_in[8];
    const int*   don_hvy_inds = (const int*)  d_in[9];
    const int*   acc_inds     = (const int*)  d_in[10];
    const int*   hyb          = (const int*)  d_in[11];
    const int*   is_h         = (const int*)  d_in[12];
    const float* lk_params    = (const float*)d_in[13];
    const int*   path_dist    = (const int*)  d_in[14];
    const float* glob         = (const float*)d_in[15];
    const float* wglob        = (const float*)d_in[16];
    const float* sp2t         = (const float*)d_in[17];
    const float* sp3t         = (const float*)d_in[18];
    const float* ringt        = (const float*)d_in[19];
    float* out = (float*)d_out;
    float* ws  = (float*)d_ws;

    lkball_kernel<<<NB, 256, 0, stream>>>(
        pose_coords, block_type, min_sep, all_bonds, bond_ranges,
        n_donH, n_acc, donH_inds, don_hvy_inds, acc_inds, hyb, is_h,
        lk_params, path_dist, glob, wglob, sp2t, sp3t, ringt, ws);

    reduce_kernel<<<1, 256, 0, stream>>>(ws, out);
}

// Round 7
// 101.800 us; speedup vs baseline: 1.2646x; 1.0487x over previous
//
#include <hip/hip_runtime.h>
#include <math.h>

// Problem constants (match reference)
constexpr int P  = 2;
constexpr int B  = 96;
constexpr int A  = 32;
constexpr int N  = B * A;      // 3072
constexpr int MD = 4;
constexpr int MA = 4;
constexpr int NPOL = MD + MA;  // 8
constexpr int SJ = 4;          // j-slices per (p,b); grid = P*B*SJ = 768 = exactly 3 blocks/CU
constexpr int JS = N / SJ;     // 768 atoms per slice
constexpr int JPT = JS / 256;  // 3 j-atoms per thread
constexpr int NB = P * B * SJ; // 768 blocks
constexpr int PB = B * SJ;     // 384 blocks per pose
constexpr float C_LK  = 0.0897935610625833f;
constexpr float LOG2E = 1.4426950408889634f;

// Measured geometry notes (rounds 2-6):
//  - SJ sweep: SJ=2 106.7, SJ=4 103.3 (best), SJ=12 106.8. 3 blocks/CU is the
//    optimum of setup-replication vs TLP.
//  - NO ordered agent-scope atomics anywhere (round-5: they emit per-block L2
//    writeback/invalidate on gfx950's non-coherent XCD L2s; 4.4x kernel bloat).
//  - Plain-store partials + separate reduce kernel; kernel boundary = coherence.
// ws layout (floats): ws[bid] = partial acc0, ws[1024+bid] = partial acc1.

__global__ __launch_bounds__(256) void lkball_kernel(
    const float* __restrict__ pose_coords,    // P*N*3
    const int*   __restrict__ block_type,     // P*B
    const int*   __restrict__ min_sep,        // P*B*B
    const int*   __restrict__ all_bonds,      // NT*A*2
    const int*   __restrict__ bond_ranges,    // NT*A*2
    const int*   __restrict__ n_donH,         // NT
    const int*   __restrict__ n_acc,          // NT
    const int*   __restrict__ donH_inds,      // NT*MD
    const int*   __restrict__ don_hvy_inds,   // NT*MD
    const int*   __restrict__ acc_inds,       // NT*MA
    const int*   __restrict__ hyb,            // NT*MA
    const int*   __restrict__ is_h,           // NT*A
    const float* __restrict__ lk_params,      // NT*A*4
    const int*   __restrict__ path_dist,      // NT*A*A
    const float* __restrict__ glob,           // cutoff, ramp2, d2_low
    const float* __restrict__ wglob,          // wdist, wang
    const float* __restrict__ sp2t,
    const float* __restrict__ sp3t,
    const float* __restrict__ ringt,
    float*       __restrict__ ws)             // per-block partials
{
    __shared__ float spolar[NPOL][16];
    __shared__ int   spath[NPOL * A];
    __shared__ float red0[4], red1[4];

    const int bid   = blockIdx.x;
    const int p     = bid / PB;
    const int rem   = bid % PB;
    const int b     = rem / SJ;
    const int slice = rem % SJ;
    const int tid   = threadIdx.x;

    // Same-address broadcast load: one L2 request for the whole wave.
    const int bt_b = block_type[p * B + b];

    // Hoist global constants to kernel entry so their (cold) loads issue
    // alongside the j-phase loads instead of after the barrier.
    const float cutoff2   = glob[0] * glob[0];
    const float inv_ramp2 = 1.0f / glob[1];
    const float c4        = (glob[2] + glob[1]) * inv_ramp2;  // (d2_low+ramp2)/ramp2

    // ---- j-register phase FIRST: zero dependence on LDS/setup, so these cold
    //      HBM loads issue immediately and overlap the polar setup chain.
    const int a_j   = tid & 31;          // constant across i (256 % 32 == 0)
    const int jbase = slice * JS + tid;

    float cx[JPT], cy[JPT], cz[JPT], rj[JPT], ve[JPT], msep_f[JPT];
    int   intra[JPT];
#pragma unroll
    for (int i = 0; i < JPT; ++i) {
        const int j   = jbase + 256 * i;
        const int b_j = j >> 5;              // constant per 32-lane group
        const float* cj = pose_coords + (size_t)(p * N + j) * 3;
        cx[i] = cj[0]; cy[i] = cj[1]; cz[i] = cj[2];
        const int bt_j = block_type[p * B + b_j];         // broadcast
        const int hv   = is_h[bt_j * A + a_j];            // coalesced
        const float4 pj = *(const float4*)(lk_params + (size_t)(bt_j * A + a_j) * 4);
        rj[i] = pj.x;
        ve[i] = hv ? 0.0f : pj.w;            // heavy-mask folded into vol_j
        msep_f[i] = (float)min_sep[(p * B + b) * B + b_j]; // broadcast
        intra[i]  = (b_j == b);
    }

    // ---- path-distance rows for all 8 polars (256 threads = 8*32), 2-hop chain
    {
        const int k  = tid >> 5;
        const int aj = tid & 31;
        const int ak = (k < MD) ? don_hvy_inds[bt_b * MD + k]
                                : acc_inds[bt_b * MA + (k - MD)];
        spath[tid] = path_dist[(bt_b * A + ak) * A + aj];
    }

    // ---- wave 0: polar records. 8 redundant 8-lane groups (k = tid&7) so the
    //      bond-graph traversal uses wave-wide __shfl on preloaded rows instead
    //      of 4 dependent cold-memory hops.
    if (tid < 64) {
        const int la = tid & 31;
        const int2 rr = *(const int2*)(bond_ranges + (size_t)(bt_b * A + la) * 2);
        const int2 bb = *(const int2*)(all_bonds   + (size_t)(bt_b * A + la) * 2);
        const int r0v = rr.x;   // bond_ranges[bt][atom=la][0]
        const int b1v = bb.y;   // all_bonds[bt][atom=la][1]

        const int k  = tid & 7;
        const int kk = k - MD;
        const bool isacc = (k >= MD);

        int a_i, valid, Hi = 0;
        if (isacc) {
            valid = (kk < n_acc[bt_b]) ? 1 : 0;
            a_i   = acc_inds[bt_b * MA + kk];
        } else {
            valid = (k < n_donH[bt_b]) ? 1 : 0;
            a_i   = don_hvy_inds[bt_b * MD + k];
            Hi    = donH_inds[bt_b * MD + k];
        }

        // Wave-uniform shuffle chain (all 64 lanes active; donors use idx 0).
        const int i0    = isacc ? (a_i & 31) : 0;
        const int r0    = __shfl(r0v, i0);
        const int base  = __shfl(b1v, r0 & 31);
        const int r0b   = __shfl(r0v, base & 31);
        const int base2 = __shfl(b1v, r0b & 31);

        // Polar params load issues in parallel with the coords loads below.
        const float4 prv = *(const float4*)(lk_params + (size_t)(bt_b * A + a_i) * 4);

        const float wdist = wglob[0];
        const float wang  = wglob[1];
        float xp[3], w0[3], w1[3];
        if (!isacc) {
            const float* hc = pose_coords + (size_t)(p * N + b * A + a_i) * 3;
            const float* Hc = pose_coords + (size_t)(p * N + b * A + Hi)  * 3;
            float dx = Hc[0] - hc[0], dy = Hc[1] - hc[1], dz = Hc[2] - hc[2];
            float inv = 1.0f / sqrtf(dx * dx + dy * dy + dz * dz + 1e-12f);
            xp[0] = hc[0]; xp[1] = hc[1]; xp[2] = hc[2];
            w0[0] = hc[0] + wdist * dx * inv;
            w0[1] = hc[1] + wdist * dy * inv;
            w0[2] = hc[2] + wdist * dz * inv;
            // donor's second water is always masked (never read in donor loop)
            w1[0] = hc[0] + 1.0e3f; w1[1] = hc[1] + 1.0e3f; w1[2] = hc[2] + 1.0e3f;
        } else {
            const float* c  = pose_coords + (size_t)(p * N + b * A + a_i)   * 3;
            const float* bx = pose_coords + (size_t)(p * N + b * A + base)  * 3;
            const float* ax = pose_coords + (size_t)(p * N + b * A + base2) * 3;

            float e1x = c[0] - bx[0], e1y = c[1] - bx[1], e1z = c[2] - bx[2];
            float inv1 = 1.0f / sqrtf(e1x * e1x + e1y * e1y + e1z * e1z + 1e-12f);
            e1x *= inv1; e1y *= inv1; e1z *= inv1;

            float ux = bx[0] - ax[0], uy = bx[1] - ax[1], uz = bx[2] - ax[2];
            float nx = uy * e1z - uz * e1y;
            float ny = uz * e1x - ux * e1z;
            float nz = ux * e1y - uy * e1x;
            float inv2 = 1.0f / sqrtf(nx * nx + ny * ny + nz * nz + 1e-12f);
            nx *= inv2; ny *= inv2; nz *= inv2;
            float e2x = ny * e1z - nz * e1y;
            float e2y = nz * e1x - nx * e1z;
            float e2z = nx * e1y - ny * e1x;

            const int hy = hyb[bt_b * MA + kk];
            const float* tab = (hy == 0) ? sp2t : ((hy == 1) ? sp3t : ringt);
            const float ct = cosf(wang), st = sinf(wang);
            float c0 = cosf(tab[0]), s0 = sinf(tab[0]);
            float c1 = cosf(tab[1]), s1 = sinf(tab[1]);

            xp[0] = c[0]; xp[1] = c[1]; xp[2] = c[2];
            w0[0] = c[0] - wdist * ct * e1x + wdist * st * c0 * e2x + wdist * st * s0 * nx;
            w0[1] = c[1] - wdist * ct * e1y + wdist * st * c0 * e2y + wdist * st * s0 * ny;
            w0[2] = c[2] - wdist * ct * e1z + wdist * st * c0 * e2z + wdist * st * s0 * nz;
            w1[0] = c[0] - wdist * ct * e1x + wdist * st * c1 * e2x + wdist * st * s1 * nx;
            w1[1] = c[1] - wdist * ct * e1y + wdist * st * c1 * e2y + wdist * st * s1 * ny;
            w1[2] = c[2] - wdist * ct * e1z + wdist * st * c1 * e2z + wdist * st * s1 * nz;
        }
        if (tid < NPOL) {   // only the first redundant copy writes
            const float lam = prv.z;
            spolar[k][0] = xp[0]; spolar[k][1] = xp[1]; spolar[k][2] = xp[2];
            spolar[k][3] = w0[0]; spolar[k][4] = w0[1]; spolar[k][5] = w0[2];
            spolar[k][6] = w1[0]; spolar[k][7] = w1[1]; spolar[k][8] = w1[2];
            spolar[k][9]  = prv.x;
            spolar[k][10] = valid ? (C_LK * prv.y / lam) : 0.0f;
            spolar[k][11] = -LOG2E / (lam * lam);
        }
    }
    __syncthreads();   // single barrier

    float acc0 = 0.0f, acc1 = 0.0f;

    // ---- Donor polars (k < MD): single water w0
#pragma unroll
    for (int k = 0; k < MD; ++k) {
        const float4 q0 = ((const float4*)spolar[k])[0];  // xp.xyz, w0.x
        const float4 q1 = ((const float4*)spolar[k])[1];  // w0.yz, w1.xy
        const float4 q2 = ((const float4*)spolar[k])[2];  // w1.z, ri, pref, negq
        const float px  = q0.x, py  = q0.y, pz  = q0.z;
        const float w0x = q0.w, w0y = q1.x, w0z = q1.y;
        const float ri  = q2.y, pref = q2.z, negq = q2.w;
        const float path_k = (float)spath[k * A + a_j];

        float rij[JPT], pv[JPT];
#pragma unroll
        for (int i = 0; i < JPT; ++i) { rij[i] = ri + rj[i]; pv[i] = pref * ve[i]; }

#pragma unroll
        for (int i = 0; i < JPT; ++i) {
            const float dx = px - cx[i], dy = py - cy[i], dz = pz - cz[i];
            float d2 = fmaf(dx, dx, fmaf(dy, dy, dz * dz));
            d2 = fmaxf(d2, 0.01f);
            const float rinv = __builtin_amdgcn_rsqf(d2);
            const float d = d2 * rinv;
            const float sep = intra[i] ? path_k : msep_f[i];
            const bool ok = (sep >= 4.0f) & (d2 < cutoff2);

            const float t = d - rij[i];
            const float e = __builtin_amdgcn_exp2f(t * t * negq);
            float lk = pv[i] * e * (rinv * rinv);
            lk = ok ? lk : 0.0f;

            const float d0x = w0x - cx[i], d0y = w0y - cy[i], d0z = w0z - cz[i];
            const float d2wmin = fmaf(d0x, d0x, fmaf(d0y, d0y, d0z * d0z));
            float wt = fmaf(d2wmin, -inv_ramp2, c4);
            wt = fminf(fmaxf(wt, 0.0f), 1.0f);
            const float frac = wt * wt * fmaf(-2.0f, wt, 3.0f);

            acc0 += lk;
            acc1 = fmaf(lk, frac, acc1);
        }
    }

    // ---- Acceptor polars (k >= MD): two waters
#pragma unroll
    for (int k = MD; k < NPOL; ++k) {
        const float4 q0 = ((const float4*)spolar[k])[0];
        const float4 q1 = ((const float4*)spolar[k])[1];
        const float4 q2 = ((const float4*)spolar[k])[2];
        const float px  = q0.x, py  = q0.y, pz  = q0.z;
        const float w0x = q0.w, w0y = q1.x, w0z = q1.y;
        const float w1x = q1.z, w1y = q1.w, w1z = q2.x;
        const float ri  = q2.y, pref = q2.z, negq = q2.w;
        const float path_k = (float)spath[k * A + a_j];

        float rij[JPT], pv[JPT];
#pragma unroll
        for (int i = 0; i < JPT; ++i) { rij[i] = ri + rj[i]; pv[i] = pref * ve[i]; }

#pragma unroll
        for (int i = 0; i < JPT; ++i) {
            const float dx = px - cx[i], dy = py - cy[i], dz = pz - cz[i];
            float d2 = fmaf(dx, dx, fmaf(dy, dy, dz * dz));
            d2 = fmaxf(d2, 0.01f);
            const float rinv = __builtin_amdgcn_rsqf(d2);
            const float d = d2 * rinv;
            const float sep = intra[i] ? path_k : msep_f[i];
            const bool ok = (sep >= 4.0f) & (d2 < cutoff2);

            const float t = d - rij[i];
            const float e = __builtin_amdgcn_exp2f(t * t * negq);
            float lk = pv[i] * e * (rinv * rinv);
            lk = ok ? lk : 0.0f;

            const float d0x = w0x - cx[i], d0y = w0y - cy[i], d0z = w0z - cz[i];
            const float d1x = w1x - cx[i], d1y = w1y - cy[i], d1z = w1z - cz[i];
            const float d2w0 = fmaf(d0x, d0x, fmaf(d0y, d0y, d0z * d0z));
            const float d2w1 = fmaf(d1x, d1x, fmaf(d1y, d1y, d1z * d1z));
            const float d2wmin = fminf(d2w0, d2w1);
            float wt = fmaf(d2wmin, -inv_ramp2, c4);
            wt = fminf(fmaxf(wt, 0.0f), 1.0f);
            const float frac = wt * wt * fmaf(-2.0f, wt, 3.0f);

            acc0 += lk;
            acc1 = fmaf(lk, frac, acc1);
        }
    }

    // ---- Reduce: wave shuffle -> LDS -> one plain store pair per block (NO atomics)
    for (int off = 32; off > 0; off >>= 1) {
        acc0 += __shfl_down(acc0, off);
        acc1 += __shfl_down(acc1, off);
    }
    const int wave = tid >> 6;
    const int lane = tid & 63;
    if (lane == 0) { red0[wave] = acc0; red1[wave] = acc1; }
    __syncthreads();
    if (tid == 0) {
        ws[bid]        = red0[0] + red0[1] + red0[2] + red0[3];
        ws[1024 + bid] = red1[0] + red1[1] + red1[2] + red1[3];
    }
}

// One block: 4 waves, one per output value, float4 loads. No atomics.
__global__ __launch_bounds__(256) void reduce_kernel(
    const float* __restrict__ ws, float* __restrict__ out)
{
    const int wave = threadIdx.x >> 6;
    const int lane = threadIdx.x & 63;
    // wave0: out[0]=acc0,p0 ws[0..383]       wave1: out[1]=acc0,p1 ws[384..767]
    // wave2: out[2]=acc1,p0 ws[1024..1407]   wave3: out[3]=acc1,p1 ws[1408..1791]
    const int base = (wave >> 1) * 1024 + (wave & 1) * PB;   // PB=384, 16B-aligned
    const float4* w4 = (const float4*)(ws + base);           // 96 float4s
    float s = 0.0f;
    for (int i = lane; i < PB / 4; i += 64) {                // 2 rounds of 64 lanes
        const float4 v = w4[i];
        s += (v.x + v.y) + (v.z + v.w);
    }
    for (int off = 32; off > 0; off >>= 1) s += __shfl_down(s, off);
    if (lane == 0) out[(wave >> 1) * P + (wave & 1)] = s;
}

extern "C" void kernel_launch(void* const* d_in, const int* in_sizes, int n_in,
                              void* d_out, int out_size, void* d_ws, size_t ws_size,
                              hipStream_t stream) {
    const float* pose_coords  = (const float*)d_in[0];
    const int*   block_type   = (const int*)  d_in[1];
    const int*   min_sep      = (const int*)  d_in[2];
    const int*   all_bonds    = (const int*)  d_in[4];
    const int*   bond_ranges  = (const int*)  d_in[5];
    const int*   n_donH       = (const int*)  d_in[6];
    const int*   n_acc        = (const int*)  d_in[7];
    const int*   donH_inds    = (const int*)  d_in[8];
    const int*   don_hvy_inds = (const int*)  d_in[9];
    const int*   acc_inds     = (const int*)  d_in[10];
    const int*   hyb          = (const int*)  d_in[11];
    const int*   is_h         = (const int*)  d_in[12];
    const float* lk_params    = (const float*)d_in[13];
    const int*   path_dist    = (const int*)  d_in[14];
    const float* glob         = (const float*)d_in[15];
    const float* wglob        = (const float*)d_in[16];
    const float* sp2t         = (const float*)d_in[17];
    const float* sp3t         = (const float*)d_in[18];
    const float* ringt        = (const float*)d_in[19];
    float* out = (float*)d_out;
    float* ws  = (float*)d_ws;

    lkball_kernel<<<NB, 256, 0, stream>>>(
        pose_coords, block_type, min_sep, all_bonds, bond_ranges,
        n_donH, n_acc, donH_inds, don_hvy_inds, acc_inds, hyb, is_h,
        lk_params, path_dist, glob, wglob, sp2t, sp3t, ringt, ws);

    reduce_kernel<<<1, 256, 0, stream>>>(ws, out);
}